// Round 17
// baseline (190.159 us; speedup 1.0000x reference)
//
#include <hip/hip_runtime.h>
#include <math.h>

#define DIM_    128
#define QH_     16
#define KVH_    4
#define WIN_    512
#define BATCH_  4
#define SEQ_    2048
#define QKV_LD  3072

// Padded workspace strides (kept from R9 — harmless).
#define QB_LD   3136   // qkvb rows (logical 3072)
#define VG_LD   2112   // vg rows   (logical 2048)
#define AH_LD   2112   // ah rows   (logical 2048)
#define WP_LD   2112   // wpth rows (logical 2048)

#define NX   (BATCH_*SEQ_*DIM_)   // 1048576
#define NWQ  (DIM_*QKV_LD)        // 393216

typedef __attribute__((ext_vector_type(8))) short short8;
typedef __attribute__((ext_vector_type(4))) float f32x4;
typedef unsigned short u16;
typedef unsigned int u32;

__device__ __forceinline__ u16 f2bf(float f) {
    u32 u = __float_as_uint(f);
    u += 0x7fff + ((u >> 16) & 1);
    return (u16)(u >> 16);
}
__device__ __forceinline__ float bf2f(u16 u) {
    return __uint_as_float(((u32)u) << 16);
}
// pack 2 f32 -> 2 bf16 (RNE), single VALU instr (no builtin on gfx950)
__device__ __forceinline__ u32 pkbf(float a, float b) {
    u32 r;
    __asm__("v_cvt_pk_bf16_f32 %0, %1, %2" : "=v"(r) : "v"(a), "v"(b));
    return r;
}
#define MFMA16 __builtin_amdgcn_mfma_f32_16x16x32_bf16

#if __has_builtin(__builtin_amdgcn_exp2f)
#define EXP2F __builtin_amdgcn_exp2f
#else
#define EXP2F exp2f
#endif

__device__ __forceinline__ void gload_lds16(const u16* g, u16* l) {
    __builtin_amdgcn_global_load_lds(
        (const __attribute__((address_space(1))) unsigned int*)(const void*)g,
        (__attribute__((address_space(3))) unsigned int*)(void*)l, 16, 0, 0);
}

// ---------- prep: xcvt + wtrans fused (unchanged) --------------------------
__global__ __launch_bounds__(256) void prep(
    const float* __restrict__ x, const float* __restrict__ Wqkv,
    const float* __restrict__ Wproj,
    u16* __restrict__ xh, u16* __restrict__ wth, u16* __restrict__ wpth)
{
    if (blockIdx.x < 1024) {
        const size_t t = (size_t)blockIdx.x * 256 + threadIdx.x;
        float4 v = *(const float4*)(x + 4 * t);
        ushort4 o;
        o.x = f2bf(v.x); o.y = f2bf(v.y); o.z = f2bf(v.z); o.w = f2bf(v.w);
        *(ushort4*)(xh + 4 * t) = o;
        return;
    }
    __shared__ float T[32][33];
    int tile = blockIdx.x - 1024;
    const float* src; u16* dst; int N, ldo;
    if (tile < 384) { src = Wqkv;  dst = wth;  N = 3072; ldo = 128; }
    else { tile -= 384; src = Wproj; dst = wpth; N = 128; ldo = WP_LD; }
    const int ntile = N >> 5;
    const int k0 = (tile / ntile) << 5, n0 = (tile % ntile) << 5;
    const int tx = threadIdx.x & 31, ty = threadIdx.x >> 5;
    #pragma unroll
    for (int i = 0; i < 4; ++i)
        T[ty + 8 * i][tx] = src[(size_t)(k0 + ty + 8 * i) * N + n0 + tx];
    __syncthreads();
    #pragma unroll
    for (int i = 0; i < 4; ++i)
        dst[(size_t)(n0 + ty + 8 * i) * ldo + k0 + tx] = f2bf(T[tx][ty + 8 * i]);
}

// ---------- GEMM1 v4: LDS-staged store epilogue (unchanged from R12) -------
__global__ __launch_bounds__(256) void gemm1_mfma(
    const u16* __restrict__ xh, const u16* __restrict__ wth,
    u16* __restrict__ qkvb, u16* __restrict__ vg)
{
    const int bn = blockIdx.x * 256;
    const int mc = blockIdx.y * 128;
    const int tid = threadIdx.x;
    const int wv = tid >> 6, lane = tid & 63;
    const int lo = lane & 15, hi = lane >> 4;
    const int lr = lo, quad = hi;
    const int wn = bn + wv * 64;               // wave's 64-col base

    __shared__ u16 Ct[2][16][264];             // 16.5KB C-tile staging

    short8 bf[4][4];                 // 64 VGPR, invariant across m
    #pragma unroll
    for (int nt = 0; nt < 4; ++nt)
        #pragma unroll
        for (int s = 0; s < 4; ++s)
            bf[nt][s] = *(const short8*)(
                wth + (size_t)(wn + nt * 16 + lo) * DIM_ + s * 32 + hi * 8);

    const bool qk = (bn < 2560);               // block-uniform
    const u16* aA = xh + (size_t)(mc + lo) * DIM_ + hi * 8;
    const int sr = tid >> 4, sc = tid & 15;    // store-phase row/lane

#define G1BODY(AF, IT) do {                                                   \
    f32x4 acc[4] = {};                                                        \
    if (qk) {                                                                 \
        _Pragma("unroll")                                                     \
        for (int s = 0; s < 4; ++s)                                           \
            _Pragma("unroll")                                                 \
            for (int nt = 0; nt < 4; ++nt)                                    \
                acc[nt] = MFMA16(bf[nt][s], AF[s], acc[nt], 0, 0, 0);         \
        const int bufq = (IT) & 1;                                            \
        _Pragma("unroll")                                                     \
        for (int nt = 0; nt < 4; ++nt) {                                      \
            uint2 o;                                                          \
            o.x = pkbf(acc[nt][0], acc[nt][1]);                               \
            o.y = pkbf(acc[nt][2], acc[nt][3]);                               \
            *(uint2*)&Ct[bufq][lr][wv * 64 + nt * 16 + quad * 4] = o;         \
        }                                                                     \
        __syncthreads();                                                      \
        const int row = mc + (IT) * 16 + sr;                                  \
        u16* drow = qkvb + (size_t)row * QB_LD + bn;                          \
        short8 v0 = *(const short8*)&Ct[bufq][sr][sc * 8];                    \
        short8 v1 = *(const short8*)&Ct[bufq][sr][128 + sc * 8];              \
        *(short8*)(drow + sc * 8) = v0;                                       \
        *(short8*)(drow + 128 + sc * 8) = v1;                                 \
    } else {                                                                  \
        _Pragma("unroll")                                                     \
        for (int s = 0; s < 4; ++s)                                           \
            _Pragma("unroll")                                                 \
            for (int nt = 0; nt < 4; ++nt)                                    \
                acc[nt] = MFMA16(AF[s], bf[nt][s], acc[nt], 0, 0, 0);         \
        const int m0 = mc + (IT) * 16 + quad * 4;                             \
        const int bb = m0 >> 11, mseq = m0 & 2047;                            \
        _Pragma("unroll")                                                     \
        for (int nt = 0; nt < 4; ++nt) {                                      \
            const int ncol = wn + nt * 16 + lr - 2560;                        \
            const int kvh = ncol >> 7, d = ncol & 127;                        \
            uint2 o;                                                          \
            o.x = pkbf(acc[nt][0], acc[nt][1]);                               \
            o.y = pkbf(acc[nt][2], acc[nt][3]);                               \
            *(uint2*)(vg + ((size_t)(bb * KVH_ + kvh) * DIM_ + d) * VG_LD     \
                      + mseq) = o;                                            \
        }                                                                     \
    }                                                                         \
} while (0)

    short8 afA[4], afB[4];
    #pragma unroll
    for (int s = 0; s < 4; ++s) afA[s] = *(const short8*)(aA + s * 32);

    #pragma unroll 1
    for (int it = 0; it < 8; it += 2) {
        const u16* aN = aA + (size_t)(it + 1) * 16 * DIM_;
        #pragma unroll
        for (int s = 0; s < 4; ++s) afB[s] = *(const short8*)(aN + s * 32);
        G1BODY(afA, it);
        const int nx = (it + 2 < 8) ? (it + 2) : 7;
        const u16* aN2 = aA + (size_t)nx * 16 * DIM_;
        #pragma unroll
        for (int s = 0; s < 4; ++s) afA[s] = *(const short8*)(aN2 + s * 32);
        G1BODY(afB, it + 1);
    }
#undef G1BODY
}

// ---------- Attention v9: 2 heads/wave -> each K/V fragment feeds 2 MFMA ---
// R13 accounting: per-round cost ~= SUM of pipes; largest term = LDS reads
// (32 ds_read_b128/wave/round, 1:1 with MFMA, identical across waves).
// v9: 4 waves x (head-pair hp, m-half mrow), each wave owns 2 heads:
// kf/vf read once, used by 2 MFMAs (2:1 MFMA:read, dep-free ILP pairs).
// Per-CU LDS traffic per round HALVES. Regs: qf[2][4]=32 + O[2][8]=64 acc
// + ~100 arch ~= 164 -> 2 waves/SIMD, 2 blocks/CU (LDS 64KB x 2 = 128KB).
// All per-head code paths (softmax, REDIST, masking) = R13-proven verbatim.
__global__ __launch_bounds__(256) void attn_mfma(
    const u16* __restrict__ qkvb, const u16* __restrict__ vg,
    u16* __restrict__ ah)
{
    const int xcd  = blockIdx.x & 7;
    const int idx  = blockIdx.x >> 3;          // 0..127 per XCD residue
    const int pair = xcd + 8 * (idx & 1);      // 0..15
    const int qt   = idx >> 1;                 // 0..63
    const int b    = pair >> 2, kvh = pair & 3;
    const int q0 = qt << 5;
    const int tid = threadIdx.x;
    const int wv4 = tid >> 6, lane = tid & 63;
    const int hp = wv4 >> 1, mrow = wv4 & 1;   // head-pair, m-half
    const int lr = lane & 15, quad = lane >> 4;
    const bool oddq = (quad & 1) != 0;

    __shared__ u16 Kb[2][16][512];   // 32KB  p = g*4+s (g=key16-grp, s=d-slice)
    __shared__ u16 Vb[2][16][512];   // 32KB  p = nt*2+kh (nt=d-blk, kh=key32-half)

    const float scale2 = 0.08838834764831845f * 1.4426950408889634f;
    float slope2[2], alpha0[2];
    #pragma unroll
    for (int u = 0; u < 2; ++u) {
        const int hu = kvh * 4 + hp * 2 + u;
        slope2[u] = exp2f(-0.5f * (float)(hu + 1)) * 1.4426950408889634f;
        const int q = q0 + mrow * 16 + lr;
        const int rm = (q < WIN_) ? q : WIN_;
        alpha0[u] = slope2[u] * (float)(q - rm);
    }
    const int jbase = max(0, q0 - WIN_);
    const int nch = (q0 + 32 - jbase + 63) >> 6;   // 1..9  (64-key chunks)
    const size_t rowb = (size_t)b * SEQ_;
    const u16* kgp = qkvb + rowb * QB_LD + (QH_ + kvh) * DIM_;
    const u16* vgb = vg + (size_t)(b * KVH_ + kvh) * DIM_ * VG_LD;
    const int lo = lane & 15, hi = lane >> 4;

    short8 qf[2][4];                 // 32 VGPR: 16 q-rows x 2 heads
    #pragma unroll
    for (int u = 0; u < 2; ++u) {
        const int hu = kvh * 4 + hp * 2 + u;
        const u16* qp = qkvb + (rowb + q0 + mrow * 16 + lr) * QB_LD
                        + hu * DIM_ + quad * 8;
        #pragma unroll
        for (int s = 0; s < 4; ++s) qf[u][s] = *(const short8*)(qp + 32 * s);
    }

    f32x4 O[2][8] = {};              // 64 AGPR: O^T per head
    float rs[2] = {0.f, 0.f};

    // 4 waves x (4 K-subs + 4 V-subs) = 32 loads/chunk, 8 per wave.
    #define STAGE(CH, SLOT) do {                                              \
        const int _jk = jbase + ((CH) << 6);                                  \
        _Pragma("unroll")                                                     \
        for (int _t = 0; _t < 4; ++_t) {                                      \
            const int _p = wv4 + _t * 4;                                      \
            int _kr = _jk + (_p >> 2) * 16 + lo;                              \
            _kr = (_kr < SEQ_) ? _kr : (SEQ_ - 1);                            \
            gload_lds16(kgp + (size_t)_kr * QB_LD + (_p & 3) * 32 + hi * 8,   \
                        &Kb[(SLOT)][_p][0]);                                  \
            int _kc = _jk + (_p & 1) * 32 + hi * 8;                           \
            _kc = (_kc < SEQ_ - 8) ? _kc : (SEQ_ - 8);                        \
            gload_lds16(vgb + (size_t)((_p >> 1) * 16 + lo) * VG_LD + _kc,    \
                        &Vb[(SLOT)][_p][0]);                                  \
        }                                                                     \
    } while (0)

    STAGE(0, 0);

    for (int ch = 0; ch < nch; ++ch) {
        const int jk = jbase + (ch << 6);
        const int slot = ch & 1;
        __asm__ volatile("s_waitcnt vmcnt(0)" ::: "memory");
        __asm__ volatile("s_barrier" ::: "memory");   // chunk ch staged; slot^1 free
        if (ch + 1 < nch) STAGE(ch + 1, slot ^ 1);

        u32 pw[2][4][2];             // [head][nt16][w] packed bf16 pairs
        const int qm0 = q0 + mrow * 16;
        #pragma unroll
        for (int nt = 0; nt < 4; ++nt) {
            f32x4 c0 = {0.f, 0.f, 0.f, 0.f}, c1 = {0.f, 0.f, 0.f, 0.f};
            __builtin_amdgcn_s_setprio(1);
            #pragma unroll
            for (int s = 0; s < 4; ++s) {
                short8 kf = *(const short8*)&Kb[slot][nt * 4 + s][lane * 8];
                c0 = MFMA16(kf, qf[0][s], c0, 0, 0, 0);
                c1 = MFMA16(kf, qf[1][s], c1, 0, 0, 0);
            }
            __builtin_amdgcn_s_setprio(0);
            const int jknt = jk + nt * 16;
            #pragma unroll
            for (int u = 0; u < 2; ++u) {
                const f32x4 c = u ? c1 : c0;
                const float b0 = fmaf(-slope2[u], (float)(jknt + quad * 4),
                                      alpha0[u]);
                float e0, e1, e2, e3;
                if (qm0 >= jknt + 15 && qm0 + 15 <= jknt + WIN_) {   // full
                    e0 = EXP2F(fmaf(c[0], scale2, b0));
                    e1 = EXP2F(fmaf(c[1], scale2, b0 - slope2[u]));
                    e2 = EXP2F(fmaf(c[2], scale2, b0 - 2.f * slope2[u]));
                    e3 = EXP2F(fmaf(c[3], scale2, b0 - 3.f * slope2[u]));
                } else {                                              // edge
                    const int q = qm0 + lr, j0q = jknt + quad * 4;
                    float ee[4];
                    #pragma unroll
                    for (int r = 0; r < 4; ++r) {
                        const int rel = q - (j0q + r);
                        const float t = fmaf(c[r], scale2,
                                             b0 - (float)r * slope2[u]);
                        ee[r] = ((unsigned)rel <= (unsigned)WIN_) ? EXP2F(t)
                                                                  : 0.f;
                    }
                    e0 = ee[0]; e1 = ee[1]; e2 = ee[2]; e3 = ee[3];
                }
                rs[u] += (e0 + e1) + (e2 + e3);
                pw[u][nt][0] = pkbf(e0, e1);
                pw[u][nt][1] = pkbf(e2, e3);
            }
        }

        // In-register P^T redistribution per head per 32-key half.
        short8 pa[2][2];
        #pragma unroll
        for (int u = 0; u < 2; ++u)
            #pragma unroll
            for (int g = 0; g < 2; ++g) {
                union { u32 w[4]; short8 s; } P;
                #pragma unroll
                for (int w = 0; w < 2; ++w) {
                    auto r = __builtin_amdgcn_permlane32_swap(
                        pw[u][2 * g][w], pw[u][2 * g + 1][w], false, false);
                    const u32 rx = r[0], ry = r[1];
                    const u32 sx = (u32)__shfl_xor((int)rx, 16);
                    const u32 sy = (u32)__shfl_xor((int)ry, 16);
                    P.w[w]     = oddq ? sy : rx;
                    P.w[2 + w] = oddq ? ry : sx;
                }
                pa[u][g] = P.s;
            }

        __builtin_amdgcn_s_setprio(1);
        #pragma unroll
        for (int nt = 0; nt < 8; ++nt) {
            short8 vf0 = *(const short8*)&Vb[slot][nt * 2][lane * 8];
            short8 vf1 = *(const short8*)&Vb[slot][nt * 2 + 1][lane * 8];
            O[0][nt] = MFMA16(vf0, pa[0][0], O[0][nt], 0, 0, 0);
            O[1][nt] = MFMA16(vf0, pa[1][0], O[1][nt], 0, 0, 0);
            O[0][nt] = MFMA16(vf1, pa[0][1], O[0][nt], 0, 0, 0);
            O[1][nt] = MFMA16(vf1, pa[1][1], O[1][nt], 0, 0, 0);
        }
        __builtin_amdgcn_s_setprio(0);
    }
    #undef STAGE

    __asm__ volatile("s_waitcnt vmcnt(0)" ::: "memory");

    #pragma unroll
    for (int u = 0; u < 2; ++u) {
        rs[u] += __shfl_xor(rs[u], 16);
        rs[u] += __shfl_xor(rs[u], 32);
    }

    #pragma unroll
    for (int u = 0; u < 2; ++u) {
        const int hu = kvh * 4 + hp * 2 + u;
        const float inv = 1.0f / rs[u];
        u16* dst = ah + (rowb + q0 + mrow * 16 + lr) * (size_t)AH_LD
                   + hu * DIM_;
        #pragma unroll
        for (int nt = 0; nt < 8; ++nt) {
            uint2 o;
            o.x = pkbf(O[u][nt][0] * inv, O[u][nt][1] * inv);
            o.y = pkbf(O[u][nt][2] * inv, O[u][nt][3] * inv);
            *(uint2*)(dst + nt * 16 + quad * 4) = o;
        }
    }
}

// ---------- GEMM2 v5 (R15 verbatim): 16-row blocks, 2 blocks/CU ------------
__global__ __launch_bounds__(512) void gemm2_mfma(
    const u16* __restrict__ ah, const u16* __restrict__ wpth,
    float* __restrict__ out)
{
    const int bm = blockIdx.x * 16;            // 512 blocks
    const int tid = threadIdx.x;
    const int wv8 = tid >> 6, lane = tid & 63;
    const int wc = wv8;                        // wave col-group (16 cols)
    const int lr = lane & 15, quad = lane >> 4;

    __shared__ u16 At2[2][16][520];            // 33.3KB

    #define G2STAGE(KS, SLOT) do {                                            \
        _Pragma("unroll")                                                     \
        for (int _t = 0; _t < 2; ++_t) {                                      \
            const int _r = wv8 * 2 + _t;                                      \
            gload_lds16(ah + (size_t)(bm + _r) * AH_LD + (KS) * 512           \
                        + lane * 8, &At2[(SLOT)][_r][0]);                     \
        }                                                                     \
    } while (0)

    f32x4 acc = {0.f, 0.f, 0.f, 0.f};

    G2STAGE(0, 0);

    #pragma unroll 1
    for (int ks = 0; ks < 4; ++ks) {
        const int slot = ks & 1;
        __asm__ volatile("s_waitcnt vmcnt(0)" ::: "memory");
        __asm__ volatile("s_barrier" ::: "memory");  // stage(ks) done everywhere
        if (ks < 3) G2STAGE(ks + 1, slot ^ 1);       // slot^1 free (ks-1 done)

        const u16* wbase = wpth + (size_t)(wc * 16 + lr) * WP_LD
                           + ks * 512 + quad * 8;
        #pragma unroll
        for (int s = 0; s < 16; ++s) {
            short8 wf = *(const short8*)(wbase + s * 32);
            short8 af = *(const short8*)&At2[slot][lr][s * 32 + quad * 8];
            acc = MFMA16(wf, af, acc, 0, 0, 0);
        }
    }
    #undef G2STAGE

    __asm__ volatile("s_waitcnt vmcnt(0)" ::: "memory");

    {
        float* orow = out + (size_t)(bm + lr) * DIM_ + wc * 16 + quad * 4;
        *(float4*)orow = *(float4*)&acc;
    }
}

// ---------- launch ----------------------------------------------------------
extern "C" void kernel_launch(void* const* d_in, const int* in_sizes, int n_in,
                              void* d_out, int out_size, void* d_ws, size_t ws_size,
                              hipStream_t stream)
{
    const float* x     = (const float*)d_in[0];
    const float* Wqkv  = (const float*)d_in[1];
    const float* Wproj = (const float*)d_in[2];
    float* out = (float*)d_out;

    u16* xh   = (u16*)d_ws;
    u16* wth  = xh   + (size_t)NX;
    u16* wpth = wth  + (size_t)NWQ;
    u16* qkvb = wpth + (size_t)DIM_ * WP_LD;                 // 128*2112
    u16* vg   = qkvb + (size_t)8192 * QB_LD;                 // 8192*3136
    u16* ahp  = vg   + (size_t)BATCH_ * KVH_ * DIM_ * VG_LD; // 16*128*2112

    prep<<<1024 + 640, 256, 0, stream>>>(x, Wqkv, Wproj, xh, wth, wpth);

    gemm1_mfma<<<dim3(12, 64), 256, 0, stream>>>(xh, wth, qkvb, vg);

    attn_mfma<<<1024, 256, 0, stream>>>(qkvb, vg, ahp);

    gemm2_mfma<<<8192 / 16, 512, 0, stream>>>(ahp, wpth, out);
}

// Round 18
// 181.775 us; speedup vs baseline: 1.0461x; 1.0461x over previous
//
#include <hip/hip_runtime.h>
#include <math.h>

#define DIM_    128
#define QH_     16
#define KVH_    4
#define WIN_    512
#define BATCH_  4
#define SEQ_    2048
#define QKV_LD  3072

// Padded workspace strides (kept from R9 — harmless).
#define QB_LD   3136   // qkvb rows (logical 3072)
#define VG_LD   2112   // vg rows   (logical 2048)
#define AH_LD   2112   // ah rows   (logical 2048)
#define WP_LD   2112   // wpth rows (logical 2048)

#define NX   (BATCH_*SEQ_*DIM_)   // 1048576
#define NWQ  (DIM_*QKV_LD)        // 393216

typedef __attribute__((ext_vector_type(8))) short short8;
typedef __attribute__((ext_vector_type(4))) float f32x4;
typedef unsigned short u16;
typedef unsigned int u32;

__device__ __forceinline__ u16 f2bf(float f) {
    u32 u = __float_as_uint(f);
    u += 0x7fff + ((u >> 16) & 1);
    return (u16)(u >> 16);
}
__device__ __forceinline__ float bf2f(u16 u) {
    return __uint_as_float(((u32)u) << 16);
}
// pack 2 f32 -> 2 bf16 (RNE), single VALU instr (no builtin on gfx950)
__device__ __forceinline__ u32 pkbf(float a, float b) {
    u32 r;
    __asm__("v_cvt_pk_bf16_f32 %0, %1, %2" : "=v"(r) : "v"(a), "v"(b));
    return r;
}
#define MFMA16 __builtin_amdgcn_mfma_f32_16x16x32_bf16

#if __has_builtin(__builtin_amdgcn_exp2f)
#define EXP2F __builtin_amdgcn_exp2f
#else
#define EXP2F exp2f
#endif

__device__ __forceinline__ void gload_lds16(const u16* g, u16* l) {
    __builtin_amdgcn_global_load_lds(
        (const __attribute__((address_space(1))) unsigned int*)(const void*)g,
        (__attribute__((address_space(3))) unsigned int*)(void*)l, 16, 0, 0);
}

// ---------- prep: xcvt + wtrans fused (unchanged) --------------------------
__global__ __launch_bounds__(256) void prep(
    const float* __restrict__ x, const float* __restrict__ Wqkv,
    const float* __restrict__ Wproj,
    u16* __restrict__ xh, u16* __restrict__ wth, u16* __restrict__ wpth)
{
    if (blockIdx.x < 1024) {
        const size_t t = (size_t)blockIdx.x * 256 + threadIdx.x;
        float4 v = *(const float4*)(x + 4 * t);
        ushort4 o;
        o.x = f2bf(v.x); o.y = f2bf(v.y); o.z = f2bf(v.z); o.w = f2bf(v.w);
        *(ushort4*)(xh + 4 * t) = o;
        return;
    }
    __shared__ float T[32][33];
    int tile = blockIdx.x - 1024;
    const float* src; u16* dst; int N, ldo;
    if (tile < 384) { src = Wqkv;  dst = wth;  N = 3072; ldo = 128; }
    else { tile -= 384; src = Wproj; dst = wpth; N = 128; ldo = WP_LD; }
    const int ntile = N >> 5;
    const int k0 = (tile / ntile) << 5, n0 = (tile % ntile) << 5;
    const int tx = threadIdx.x & 31, ty = threadIdx.x >> 5;
    #pragma unroll
    for (int i = 0; i < 4; ++i)
        T[ty + 8 * i][tx] = src[(size_t)(k0 + ty + 8 * i) * N + n0 + tx];
    __syncthreads();
    #pragma unroll
    for (int i = 0; i < 4; ++i)
        dst[(size_t)(n0 + ty + 8 * i) * ldo + k0 + tx] = f2bf(T[tx][ty + 8 * i]);
}

// ---------- GEMM1 v4: LDS-staged store epilogue (unchanged from R12) -------
__global__ __launch_bounds__(256) void gemm1_mfma(
    const u16* __restrict__ xh, const u16* __restrict__ wth,
    u16* __restrict__ qkvb, u16* __restrict__ vg)
{
    const int bn = blockIdx.x * 256;
    const int mc = blockIdx.y * 128;
    const int tid = threadIdx.x;
    const int wv = tid >> 6, lane = tid & 63;
    const int lo = lane & 15, hi = lane >> 4;
    const int lr = lo, quad = hi;
    const int wn = bn + wv * 64;               // wave's 64-col base

    __shared__ u16 Ct[2][16][264];             // 16.5KB C-tile staging

    short8 bf[4][4];                 // 64 VGPR, invariant across m
    #pragma unroll
    for (int nt = 0; nt < 4; ++nt)
        #pragma unroll
        for (int s = 0; s < 4; ++s)
            bf[nt][s] = *(const short8*)(
                wth + (size_t)(wn + nt * 16 + lo) * DIM_ + s * 32 + hi * 8);

    const bool qk = (bn < 2560);               // block-uniform
    const u16* aA = xh + (size_t)(mc + lo) * DIM_ + hi * 8;
    const int sr = tid >> 4, sc = tid & 15;    // store-phase row/lane

#define G1BODY(AF, IT) do {                                                   \
    f32x4 acc[4] = {};                                                        \
    if (qk) {                                                                 \
        _Pragma("unroll")                                                     \
        for (int s = 0; s < 4; ++s)                                           \
            _Pragma("unroll")                                                 \
            for (int nt = 0; nt < 4; ++nt)                                    \
                acc[nt] = MFMA16(bf[nt][s], AF[s], acc[nt], 0, 0, 0);         \
        const int bufq = (IT) & 1;                                            \
        _Pragma("unroll")                                                     \
        for (int nt = 0; nt < 4; ++nt) {                                      \
            uint2 o;                                                          \
            o.x = pkbf(acc[nt][0], acc[nt][1]);                               \
            o.y = pkbf(acc[nt][2], acc[nt][3]);                               \
            *(uint2*)&Ct[bufq][lr][wv * 64 + nt * 16 + quad * 4] = o;         \
        }                                                                     \
        __syncthreads();                                                      \
        const int row = mc + (IT) * 16 + sr;                                  \
        u16* drow = qkvb + (size_t)row * QB_LD + bn;                          \
        short8 v0 = *(const short8*)&Ct[bufq][sr][sc * 8];                    \
        short8 v1 = *(const short8*)&Ct[bufq][sr][128 + sc * 8];              \
        *(short8*)(drow + sc * 8) = v0;                                       \
        *(short8*)(drow + 128 + sc * 8) = v1;                                 \
    } else {                                                                  \
        _Pragma("unroll")                                                     \
        for (int s = 0; s < 4; ++s)                                           \
            _Pragma("unroll")                                                 \
            for (int nt = 0; nt < 4; ++nt)                                    \
                acc[nt] = MFMA16(AF[s], bf[nt][s], acc[nt], 0, 0, 0);         \
        const int m0 = mc + (IT) * 16 + quad * 4;                             \
        const int bb = m0 >> 11, mseq = m0 & 2047;                            \
        _Pragma("unroll")                                                     \
        for (int nt = 0; nt < 4; ++nt) {                                      \
            const int ncol = wn + nt * 16 + lr - 2560;                        \
            const int kvh = ncol >> 7, d = ncol & 127;                        \
            uint2 o;                                                          \
            o.x = pkbf(acc[nt][0], acc[nt][1]);                               \
            o.y = pkbf(acc[nt][2], acc[nt][3]);                               \
            *(uint2*)(vg + ((size_t)(bb * KVH_ + kvh) * DIM_ + d) * VG_LD     \
                      + mseq) = o;                                            \
        }                                                                     \
    }                                                                         \
} while (0)

    short8 afA[4], afB[4];
    #pragma unroll
    for (int s = 0; s < 4; ++s) afA[s] = *(const short8*)(aA + s * 32);

    #pragma unroll 1
    for (int it = 0; it < 8; it += 2) {
        const u16* aN = aA + (size_t)(it + 1) * 16 * DIM_;
        #pragma unroll
        for (int s = 0; s < 4; ++s) afB[s] = *(const short8*)(aN + s * 32);
        G1BODY(afA, it);
        const int nx = (it + 2 < 8) ? (it + 2) : 7;
        const u16* aN2 = aA + (size_t)nx * 16 * DIM_;
        #pragma unroll
        for (int s = 0; s < 4; ++s) afA[s] = *(const short8*)(aN2 + s * 32);
        G1BODY(afB, it + 1);
    }
#undef G1BODY
}

// ---------- Attention v10: 64-row q-tiles, 16 waves, v7 per-wave code ------
// R17 law: never drop below 4 waves/SIMD (v9: 2 waves/SIMD regressed 13us).
// v10 keeps v7's per-wave structure byte-identical (4 waves/SIMD at ~92
// regs) and doubles work per sync round along the Q axis: 64-row tiles,
// 16 waves (1024 thr), wave = (head hq, m-quarter mq). Each staged 64-key
// chunk feeds 64 q-rows -> staging bytes, barriers, vmcnt drains PER ROW
// halve (rounds per 32 rows: 9 -> 5; FETCH ~24.6 -> ~15MB). Cost: 1
// block/CU (vs 2) — but per-SIMD wave count, the quantity R17 proved
// matters, is unchanged.
__global__ __launch_bounds__(1024) void attn_mfma(
    const u16* __restrict__ qkvb, const u16* __restrict__ vg,
    u16* __restrict__ ah)
{
    const int xcd  = blockIdx.x & 7;
    const int idx  = blockIdx.x >> 3;          // 0..63 per XCD residue
    const int pair = xcd + 8 * (idx & 1);      // 0..15
    const int qt   = idx >> 1;                 // 0..31
    const int b    = pair >> 2, kvh = pair & 3;
    const int q0 = qt << 6;                    // 64-row q-tiles
    const int tid = threadIdx.x;
    const int wv16 = tid >> 6, lane = tid & 63;
    const int hq = wv16 >> 2, mq = wv16 & 3;   // head-sub, m-quarter
    const int lr = lane & 15, quad = lane >> 4;
    const int h = kvh * 4 + hq;
    const bool oddq = (quad & 1) != 0;

    __shared__ u16 Kb[2][16][512];   // 32KB  p = g*4+s (g=key16-grp, s=d-slice)
    __shared__ u16 Vb[2][16][512];   // 32KB  p = nt*2+kh (nt=d-blk, kh=key32-half)

    const float scale2 = 0.08838834764831845f * 1.4426950408889634f;
    const float slope2 = exp2f(-0.5f * (float)(h + 1)) * 1.4426950408889634f;
    const int jbase = max(0, q0 - WIN_);
    const int nch = (q0 + 64 - jbase + 63) >> 6;   // 2..10 (64-key chunks)
    const size_t rowb = (size_t)b * SEQ_;
    const u16* kgp = qkvb + rowb * QB_LD + (QH_ + kvh) * DIM_;
    const u16* vgb = vg + (size_t)(b * KVH_ + kvh) * DIM_ * VG_LD;
    const int lo = lane & 15, hi = lane >> 4;

    short8 qf[4];                    // 16 VGPR: this wave's 16 q-rows
    {
        const u16* qp = qkvb + (rowb + q0 + mq * 16 + lr) * QB_LD
                        + h * DIM_ + quad * 8;
        #pragma unroll
        for (int s = 0; s < 4; ++s) qf[s] = *(const short8*)(qp + 32 * s);
    }

    float alpha0;
    {
        const int q = q0 + mq * 16 + lr;
        const int rm = (q < WIN_) ? q : WIN_;
        alpha0 = slope2 * (float)(q - rm);
    }

    f32x4 O[8] = {};                 // 32 AGPR: O^T, regs = d, lane col = q
    float rs = 0.f;

    // 16 waves x (1 K-sub + 1 V-sub) = 32 loads/chunk, 2 per wave.
    #define STAGE(CH, SLOT) do {                                              \
        const int _jk = jbase + ((CH) << 6);                                  \
        const int _p = wv16;                                                  \
        int _kr = _jk + (_p >> 2) * 16 + lo;                                  \
        _kr = (_kr < SEQ_) ? _kr : (SEQ_ - 1);                                \
        gload_lds16(kgp + (size_t)_kr * QB_LD + (_p & 3) * 32 + hi * 8,       \
                    &Kb[(SLOT)][_p][0]);                                      \
        int _kc = _jk + (_p & 1) * 32 + hi * 8;                               \
        _kc = (_kc < SEQ_ - 8) ? _kc : (SEQ_ - 8);                            \
        gload_lds16(vgb + (size_t)((_p >> 1) * 16 + lo) * VG_LD + _kc,        \
                    &Vb[(SLOT)][_p][0]);                                      \
    } while (0)

    STAGE(0, 0);

    for (int ch = 0; ch < nch; ++ch) {
        const int jk = jbase + (ch << 6);
        const int slot = ch & 1;
        __asm__ volatile("s_waitcnt vmcnt(0)" ::: "memory");
        __asm__ volatile("s_barrier" ::: "memory");   // chunk ch staged; slot^1 free
        if (ch + 1 < nch) STAGE(ch + 1, slot ^ 1);

        u32 pw[4][2];                // [nt16][w] packed bf16 pairs
        const int qm0 = q0 + mq * 16;
        #pragma unroll
        for (int nt = 0; nt < 4; ++nt) {
            f32x4 c = {0.f, 0.f, 0.f, 0.f};
            __builtin_amdgcn_s_setprio(1);
            #pragma unroll
            for (int s = 0; s < 4; ++s) {
                short8 kf = *(const short8*)&Kb[slot][nt * 4 + s][lane * 8];
                c = MFMA16(kf, qf[s], c, 0, 0, 0);
            }
            __builtin_amdgcn_s_setprio(0);
            const int jknt = jk + nt * 16;
            const float b0 = fmaf(-slope2, (float)(jknt + quad * 4), alpha0);
            float e0, e1, e2, e3;
            if (qm0 >= jknt + 15 && qm0 + 15 <= jknt + WIN_) {   // full
                e0 = EXP2F(fmaf(c[0], scale2, b0));
                e1 = EXP2F(fmaf(c[1], scale2, b0 - slope2));
                e2 = EXP2F(fmaf(c[2], scale2, b0 - 2.f * slope2));
                e3 = EXP2F(fmaf(c[3], scale2, b0 - 3.f * slope2));
            } else {                                              // edge
                const int q = qm0 + lr, j0q = jknt + quad * 4;
                float ee[4];
                #pragma unroll
                for (int r = 0; r < 4; ++r) {
                    const int rel = q - (j0q + r);
                    const float t = fmaf(c[r], scale2, b0 - (float)r * slope2);
                    ee[r] = ((unsigned)rel <= (unsigned)WIN_) ? EXP2F(t) : 0.f;
                }
                e0 = ee[0]; e1 = ee[1]; e2 = ee[2]; e3 = ee[3];
            }
            rs += (e0 + e1) + (e2 + e3);
            pw[nt][0] = pkbf(e0, e1);
            pw[nt][1] = pkbf(e2, e3);
        }

        // In-register P^T redistribution, one per 32-key half (R4 algebra).
        short8 pa[2];
        #pragma unroll
        for (int g = 0; g < 2; ++g) {
            union { u32 w[4]; short8 s; } P;
            #pragma unroll
            for (int w = 0; w < 2; ++w) {
                auto r = __builtin_amdgcn_permlane32_swap(
                    pw[2 * g][w], pw[2 * g + 1][w], false, false);
                const u32 rx = r[0], ry = r[1];
                const u32 sx = (u32)__shfl_xor((int)rx, 16);
                const u32 sy = (u32)__shfl_xor((int)ry, 16);
                P.w[w]     = oddq ? sy : rx;
                P.w[2 + w] = oddq ? ry : sx;
            }
            pa[g] = P.s;
        }

        __builtin_amdgcn_s_setprio(1);
        #pragma unroll
        for (int nt = 0; nt < 8; ++nt) {
            short8 vf0 = *(const short8*)&Vb[slot][nt * 2][lane * 8];
            short8 vf1 = *(const short8*)&Vb[slot][nt * 2 + 1][lane * 8];
            O[nt] = MFMA16(vf0, pa[0], O[nt], 0, 0, 0);
            O[nt] = MFMA16(vf1, pa[1], O[nt], 0, 0, 0);
        }
        __builtin_amdgcn_s_setprio(0);
    }
    #undef STAGE

    __asm__ volatile("s_waitcnt vmcnt(0)" ::: "memory");

    rs += __shfl_xor(rs, 16);
    rs += __shfl_xor(rs, 32);

    {
        const float inv = 1.0f / rs;
        u16* dst = ah + (rowb + q0 + mq * 16 + lr) * (size_t)AH_LD
                   + h * DIM_;
        #pragma unroll
        for (int nt = 0; nt < 8; ++nt) {
            uint2 o;
            o.x = pkbf(O[nt][0] * inv, O[nt][1] * inv);
            o.y = pkbf(O[nt][2] * inv, O[nt][3] * inv);
            *(uint2*)(dst + nt * 16 + quad * 4) = o;
        }
    }
}

// ---------- GEMM2 v5 (R15 verbatim): 16-row blocks, 2 blocks/CU ------------
__global__ __launch_bounds__(512) void gemm2_mfma(
    const u16* __restrict__ ah, const u16* __restrict__ wpth,
    float* __restrict__ out)
{
    const int bm = blockIdx.x * 16;            // 512 blocks
    const int tid = threadIdx.x;
    const int wv8 = tid >> 6, lane = tid & 63;
    const int wc = wv8;                        // wave col-group (16 cols)
    const int lr = lane & 15, quad = lane >> 4;

    __shared__ u16 At2[2][16][520];            // 33.3KB

    #define G2STAGE(KS, SLOT) do {                                            \
        _Pragma("unroll")                                                     \
        for (int _t = 0; _t < 2; ++_t) {                                      \
            const int _r = wv8 * 2 + _t;                                      \
            gload_lds16(ah + (size_t)(bm + _r) * AH_LD + (KS) * 512           \
                        + lane * 8, &At2[(SLOT)][_r][0]);                     \
        }                                                                     \
    } while (0)

    f32x4 acc = {0.f, 0.f, 0.f, 0.f};

    G2STAGE(0, 0);

    #pragma unroll 1
    for (int ks = 0; ks < 4; ++ks) {
        const int slot = ks & 1;
        __asm__ volatile("s_waitcnt vmcnt(0)" ::: "memory");
        __asm__ volatile("s_barrier" ::: "memory");  // stage(ks) done everywhere
        if (ks < 3) G2STAGE(ks + 1, slot ^ 1);       // slot^1 free (ks-1 done)

        const u16* wbase = wpth + (size_t)(wc * 16 + lr) * WP_LD
                           + ks * 512 + quad * 8;
        #pragma unroll
        for (int s = 0; s < 16; ++s) {
            short8 wf = *(const short8*)(wbase + s * 32);
            short8 af = *(const short8*)&At2[slot][lr][s * 32 + quad * 8];
            acc = MFMA16(wf, af, acc, 0, 0, 0);
        }
    }
    #undef G2STAGE

    __asm__ volatile("s_waitcnt vmcnt(0)" ::: "memory");

    {
        float* orow = out + (size_t)(bm + lr) * DIM_ + wc * 16 + quad * 4;
        *(float4*)orow = *(float4*)&acc;
    }
}

// ---------- launch ----------------------------------------------------------
extern "C" void kernel_launch(void* const* d_in, const int* in_sizes, int n_in,
                              void* d_out, int out_size, void* d_ws, size_t ws_size,
                              hipStream_t stream)
{
    const float* x     = (const float*)d_in[0];
    const float* Wqkv  = (const float*)d_in[1];
    const float* Wproj = (const float*)d_in[2];
    float* out = (float*)d_out;

    u16* xh   = (u16*)d_ws;
    u16* wth  = xh   + (size_t)NX;
    u16* wpth = wth  + (size_t)NWQ;
    u16* qkvb = wpth + (size_t)DIM_ * WP_LD;                 // 128*2112
    u16* vg   = qkvb + (size_t)8192 * QB_LD;                 // 8192*3136
    u16* ahp  = vg   + (size_t)BATCH_ * KVH_ * DIM_ * VG_LD; // 16*128*2112

    prep<<<1024 + 640, 256, 0, stream>>>(x, Wqkv, Wproj, xh, wth, wpth);

    gemm1_mfma<<<dim3(12, 64), 256, 0, stream>>>(xh, wth, qkvb, vg);

    attn_mfma<<<512, 1024, 0, stream>>>(qkvb, vg, ahp);

    gemm2_mfma<<<8192 / 16, 512, 0, stream>>>(ahp, wpth, out);
}

// Round 19
// 178.786 us; speedup vs baseline: 1.0636x; 1.0167x over previous
//
#include <hip/hip_runtime.h>
#include <math.h>

#define DIM_    128
#define QH_     16
#define KVH_    4
#define WIN_    512
#define BATCH_  4
#define SEQ_    2048
#define QKV_LD  3072

// Padded workspace strides (kept from R9 — harmless).
#define QB_LD   3136   // qkvb rows (logical 3072)
#define VG_LD   2112   // vg rows   (logical 2048)
#define AH_LD   2112   // ah rows   (logical 2048)
#define WP_LD   2112   // wpth rows (logical 2048)

#define NX   (BATCH_*SEQ_*DIM_)   // 1048576
#define NWQ  (DIM_*QKV_LD)        // 393216

typedef __attribute__((ext_vector_type(8))) short short8;
typedef __attribute__((ext_vector_type(4))) float f32x4;
typedef unsigned short u16;
typedef unsigned int u32;

__device__ __forceinline__ u16 f2bf(float f) {
    u32 u = __float_as_uint(f);
    u += 0x7fff + ((u >> 16) & 1);
    return (u16)(u >> 16);
}
__device__ __forceinline__ float bf2f(u16 u) {
    return __uint_as_float(((u32)u) << 16);
}
// pack 2 f32 -> 2 bf16 (RNE), single VALU instr (no builtin on gfx950)
__device__ __forceinline__ u32 pkbf(float a, float b) {
    u32 r;
    __asm__("v_cvt_pk_bf16_f32 %0, %1, %2" : "=v"(r) : "v"(a), "v"(b));
    return r;
}
#define MFMA16 __builtin_amdgcn_mfma_f32_16x16x32_bf16

#if __has_builtin(__builtin_amdgcn_exp2f)
#define EXP2F __builtin_amdgcn_exp2f
#else
#define EXP2F exp2f
#endif

__device__ __forceinline__ void gload_lds16(const u16* g, u16* l) {
    __builtin_amdgcn_global_load_lds(
        (const __attribute__((address_space(1))) unsigned int*)(const void*)g,
        (__attribute__((address_space(3))) unsigned int*)(void*)l, 16, 0, 0);
}

// ---------- prep: xcvt + wtrans fused --------------------------------------
__global__ __launch_bounds__(256) void prep(
    const float* __restrict__ x, const float* __restrict__ Wqkv,
    const float* __restrict__ Wproj,
    u16* __restrict__ xh, u16* __restrict__ wth, u16* __restrict__ wpth)
{
    if (blockIdx.x < 1024) {
        const size_t t = (size_t)blockIdx.x * 256 + threadIdx.x;
        float4 v = *(const float4*)(x + 4 * t);
        ushort4 o;
        o.x = f2bf(v.x); o.y = f2bf(v.y); o.z = f2bf(v.z); o.w = f2bf(v.w);
        *(ushort4*)(xh + 4 * t) = o;
        return;
    }
    __shared__ float T[32][33];
    int tile = blockIdx.x - 1024;
    const float* src; u16* dst; int N, ldo;
    if (tile < 384) { src = Wqkv;  dst = wth;  N = 3072; ldo = 128; }
    else { tile -= 384; src = Wproj; dst = wpth; N = 128; ldo = WP_LD; }
    const int ntile = N >> 5;
    const int k0 = (tile / ntile) << 5, n0 = (tile % ntile) << 5;
    const int tx = threadIdx.x & 31, ty = threadIdx.x >> 5;
    #pragma unroll
    for (int i = 0; i < 4; ++i)
        T[ty + 8 * i][tx] = src[(size_t)(k0 + ty + 8 * i) * N + n0 + tx];
    __syncthreads();
    #pragma unroll
    for (int i = 0; i < 4; ++i)
        dst[(size_t)(n0 + ty + 8 * i) * ldo + k0 + tx] = f2bf(T[tx][ty + 8 * i]);
}

// ---------- GEMM1 v4: LDS-staged store epilogue (R12-proven) ---------------
__global__ __launch_bounds__(256) void gemm1_mfma(
    const u16* __restrict__ xh, const u16* __restrict__ wth,
    u16* __restrict__ qkvb, u16* __restrict__ vg)
{
    const int bn = blockIdx.x * 256;
    const int mc = blockIdx.y * 128;
    const int tid = threadIdx.x;
    const int wv = tid >> 6, lane = tid & 63;
    const int lo = lane & 15, hi = lane >> 4;
    const int lr = lo, quad = hi;
    const int wn = bn + wv * 64;               // wave's 64-col base

    __shared__ u16 Ct[2][16][264];             // 16.5KB C-tile staging

    short8 bf[4][4];                 // 64 VGPR, invariant across m
    #pragma unroll
    for (int nt = 0; nt < 4; ++nt)
        #pragma unroll
        for (int s = 0; s < 4; ++s)
            bf[nt][s] = *(const short8*)(
                wth + (size_t)(wn + nt * 16 + lo) * DIM_ + s * 32 + hi * 8);

    const bool qk = (bn < 2560);               // block-uniform
    const u16* aA = xh + (size_t)(mc + lo) * DIM_ + hi * 8;
    const int sr = tid >> 4, sc = tid & 15;    // store-phase row/lane

#define G1BODY(AF, IT) do {                                                   \
    f32x4 acc[4] = {};                                                        \
    if (qk) {                                                                 \
        _Pragma("unroll")                                                     \
        for (int s = 0; s < 4; ++s)                                           \
            _Pragma("unroll")                                                 \
            for (int nt = 0; nt < 4; ++nt)                                    \
                acc[nt] = MFMA16(bf[nt][s], AF[s], acc[nt], 0, 0, 0);         \
        const int bufq = (IT) & 1;                                            \
        _Pragma("unroll")                                                     \
        for (int nt = 0; nt < 4; ++nt) {                                      \
            uint2 o;                                                          \
            o.x = pkbf(acc[nt][0], acc[nt][1]);                               \
            o.y = pkbf(acc[nt][2], acc[nt][3]);                               \
            *(uint2*)&Ct[bufq][lr][wv * 64 + nt * 16 + quad * 4] = o;         \
        }                                                                     \
        __syncthreads();                                                      \
        const int row = mc + (IT) * 16 + sr;                                  \
        u16* drow = qkvb + (size_t)row * QB_LD + bn;                          \
        short8 v0 = *(const short8*)&Ct[bufq][sr][sc * 8];                    \
        short8 v1 = *(const short8*)&Ct[bufq][sr][128 + sc * 8];              \
        *(short8*)(drow + sc * 8) = v0;                                       \
        *(short8*)(drow + 128 + sc * 8) = v1;                                 \
    } else {                                                                  \
        _Pragma("unroll")                                                     \
        for (int s = 0; s < 4; ++s)                                           \
            _Pragma("unroll")                                                 \
            for (int nt = 0; nt < 4; ++nt)                                    \
                acc[nt] = MFMA16(AF[s], bf[nt][s], acc[nt], 0, 0, 0);         \
        const int m0 = mc + (IT) * 16 + quad * 4;                             \
        const int bb = m0 >> 11, mseq = m0 & 2047;                            \
        _Pragma("unroll")                                                     \
        for (int nt = 0; nt < 4; ++nt) {                                      \
            const int ncol = wn + nt * 16 + lr - 2560;                        \
            const int kvh = ncol >> 7, d = ncol & 127;                        \
            uint2 o;                                                          \
            o.x = pkbf(acc[nt][0], acc[nt][1]);                               \
            o.y = pkbf(acc[nt][2], acc[nt][3]);                               \
            *(uint2*)(vg + ((size_t)(bb * KVH_ + kvh) * DIM_ + d) * VG_LD     \
                      + mseq) = o;                                            \
        }                                                                     \
    }                                                                         \
} while (0)

    short8 afA[4], afB[4];
    #pragma unroll
    for (int s = 0; s < 4; ++s) afA[s] = *(const short8*)(aA + s * 32);

    #pragma unroll 1
    for (int it = 0; it < 8; it += 2) {
        const u16* aN = aA + (size_t)(it + 1) * 16 * DIM_;
        #pragma unroll
        for (int s = 0; s < 4; ++s) afB[s] = *(const short8*)(aN + s * 32);
        G1BODY(afA, it);
        const int nx = (it + 2 < 8) ? (it + 2) : 7;
        const u16* aN2 = aA + (size_t)nx * 16 * DIM_;
        #pragma unroll
        for (int s = 0; s < 4; ++s) afA[s] = *(const short8*)(aN2 + s * 32);
        G1BODY(afB, it + 1);
    }
#undef G1BODY
}

// ---------- Attention v7 (R13/R15-proven): 64-key chunks, 2-slot ring ------
// Final form. Plateau map: 68.6-70us across 32/64-row tiles, 17/33% occ,
// 32/64-key chunks; regressions only when waves/SIMD<4 (R17) or when
// hand-scheduling inflated registers (R14). Sits ~15% above its
// sum-of-pipes bound (MFMA~13 + VALU-softmax~22 + DS~25us).
__global__ __launch_bounds__(512) void attn_mfma(
    const u16* __restrict__ qkvb, const u16* __restrict__ vg,
    u16* __restrict__ ah)
{
    const int xcd  = blockIdx.x & 7;
    const int idx  = blockIdx.x >> 3;          // 0..127 per XCD residue
    const int pair = xcd + 8 * (idx & 1);      // 0..15
    const int qt   = idx >> 1;                 // 0..63
    const int b    = pair >> 2, kvh = pair & 3;
    const int q0 = qt << 5;
    const int tid = threadIdx.x;
    const int wv8 = tid >> 6, lane = tid & 63;
    const int hq = wv8 >> 1, mrow = wv8 & 1;   // head-sub, m-half
    const int lr = lane & 15, quad = lane >> 4;
    const int h = kvh * 4 + hq;
    const bool oddq = (quad & 1) != 0;

    __shared__ u16 Kb[2][16][512];   // 32KB  p = g*4+s (g=key16-grp, s=d-slice)
    __shared__ u16 Vb[2][16][512];   // 32KB  p = nt*2+kh (nt=d-blk, kh=key32-half)

    const float scale2 = 0.08838834764831845f * 1.4426950408889634f;
    const float slope2 = exp2f(-0.5f * (float)(h + 1)) * 1.4426950408889634f;
    const int jbase = max(0, q0 - WIN_);
    const int nch = (q0 + 32 - jbase + 63) >> 6;   // 1..9  (64-key chunks)
    const size_t rowb = (size_t)b * SEQ_;
    const u16* kgp = qkvb + rowb * QB_LD + (QH_ + kvh) * DIM_;
    const u16* vgb = vg + (size_t)(b * KVH_ + kvh) * DIM_ * VG_LD;
    const int lo = lane & 15, hi = lane >> 4;

    short8 qf[4];                    // 16 VGPR: this wave's 16 q-rows
    {
        const u16* qp = qkvb + (rowb + q0 + mrow * 16 + lr) * QB_LD
                        + h * DIM_ + quad * 8;
        #pragma unroll
        for (int s = 0; s < 4; ++s) qf[s] = *(const short8*)(qp + 32 * s);
    }

    float alpha0;
    {
        const int q = q0 + mrow * 16 + lr;
        const int rm = (q < WIN_) ? q : WIN_;
        alpha0 = slope2 * (float)(q - rm);
    }

    f32x4 O[8] = {};                 // 32 AGPR: O^T, regs = d, lane col = q
    float rs = 0.f;

    #define STAGE(CH, SLOT) do {                                              \
        const int _jk = jbase + ((CH) << 6);                                  \
        _Pragma("unroll")                                                     \
        for (int _t = 0; _t < 2; ++_t) {                                      \
            const int _p = wv8 + _t * 8;                                      \
            int _kr = _jk + (_p >> 2) * 16 + lo;                              \
            _kr = (_kr < SEQ_) ? _kr : (SEQ_ - 1);                            \
            gload_lds16(kgp + (size_t)_kr * QB_LD + (_p & 3) * 32 + hi * 8,   \
                        &Kb[(SLOT)][_p][0]);                                  \
            int _kc = _jk + (_p & 1) * 32 + hi * 8;                           \
            _kc = (_kc < SEQ_ - 8) ? _kc : (SEQ_ - 8);                        \
            gload_lds16(vgb + (size_t)((_p >> 1) * 16 + lo) * VG_LD + _kc,    \
                        &Vb[(SLOT)][_p][0]);                                  \
        }                                                                     \
    } while (0)

    STAGE(0, 0);

    for (int ch = 0; ch < nch; ++ch) {
        const int jk = jbase + (ch << 6);
        const int slot = ch & 1;
        __asm__ volatile("s_waitcnt vmcnt(0)" ::: "memory");
        __asm__ volatile("s_barrier" ::: "memory");   // chunk ch staged; slot^1 free
        if (ch + 1 < nch) STAGE(ch + 1, slot ^ 1);

        u32 pw[4][2];                // [nt16][w] packed bf16 pairs
        const int qm0 = q0 + mrow * 16;
        #pragma unroll
        for (int nt = 0; nt < 4; ++nt) {
            f32x4 c = {0.f, 0.f, 0.f, 0.f};
            __builtin_amdgcn_s_setprio(1);
            #pragma unroll
            for (int s = 0; s < 4; ++s) {
                short8 kf = *(const short8*)&Kb[slot][nt * 4 + s][lane * 8];
                c = MFMA16(kf, qf[s], c, 0, 0, 0);
            }
            __builtin_amdgcn_s_setprio(0);
            const int jknt = jk + nt * 16;
            const float b0 = fmaf(-slope2, (float)(jknt + quad * 4), alpha0);
            float e0, e1, e2, e3;
            if (qm0 >= jknt + 15 && qm0 + 15 <= jknt + WIN_) {   // full
                e0 = EXP2F(fmaf(c[0], scale2, b0));
                e1 = EXP2F(fmaf(c[1], scale2, b0 - slope2));
                e2 = EXP2F(fmaf(c[2], scale2, b0 - 2.f * slope2));
                e3 = EXP2F(fmaf(c[3], scale2, b0 - 3.f * slope2));
            } else {                                              // edge
                const int q = qm0 + lr, j0q = jknt + quad * 4;
                float ee[4];
                #pragma unroll
                for (int r = 0; r < 4; ++r) {
                    const int rel = q - (j0q + r);
                    const float t = fmaf(c[r], scale2, b0 - (float)r * slope2);
                    ee[r] = ((unsigned)rel <= (unsigned)WIN_) ? EXP2F(t) : 0.f;
                }
                e0 = ee[0]; e1 = ee[1]; e2 = ee[2]; e3 = ee[3];
            }
            rs += (e0 + e1) + (e2 + e3);
            pw[nt][0] = pkbf(e0, e1);
            pw[nt][1] = pkbf(e2, e3);
        }

        // In-register P^T redistribution, one per 32-key half (R4 algebra).
        short8 pa[2];
        #pragma unroll
        for (int g = 0; g < 2; ++g) {
            union { u32 w[4]; short8 s; } P;
            #pragma unroll
            for (int w = 0; w < 2; ++w) {
                auto r = __builtin_amdgcn_permlane32_swap(
                    pw[2 * g][w], pw[2 * g + 1][w], false, false);
                const u32 rx = r[0], ry = r[1];
                const u32 sx = (u32)__shfl_xor((int)rx, 16);
                const u32 sy = (u32)__shfl_xor((int)ry, 16);
                P.w[w]     = oddq ? sy : rx;
                P.w[2 + w] = oddq ? ry : sx;
            }
            pa[g] = P.s;
        }

        __builtin_amdgcn_s_setprio(1);
        #pragma unroll
        for (int nt = 0; nt < 8; ++nt) {
            short8 vf0 = *(const short8*)&Vb[slot][nt * 2][lane * 8];
            short8 vf1 = *(const short8*)&Vb[slot][nt * 2 + 1][lane * 8];
            O[nt] = MFMA16(vf0, pa[0], O[nt], 0, 0, 0);
            O[nt] = MFMA16(vf1, pa[1], O[nt], 0, 0, 0);
        }
        __builtin_amdgcn_s_setprio(0);
    }
    #undef STAGE

    __asm__ volatile("s_waitcnt vmcnt(0)" ::: "memory");

    rs += __shfl_xor(rs, 16);
    rs += __shfl_xor(rs, 32);

    {
        const float inv = 1.0f / rs;
        u16* dst = ah + (rowb + q0 + mrow * 16 + lr) * (size_t)AH_LD
                   + h * DIM_;
        #pragma unroll
        for (int nt = 0; nt < 8; ++nt) {
            uint2 o;
            o.x = pkbf(O[nt][0] * inv, O[nt][1] * inv);
            o.y = pkbf(O[nt][2] * inv, O[nt][3] * inv);
            *(uint2*)(dst + nt * 16 + quad * 4) = o;
        }
    }
}

// ---------- GEMM2 v5 (R15-proven): 16-row blocks, 2 blocks/CU --------------
__global__ __launch_bounds__(512) void gemm2_mfma(
    const u16* __restrict__ ah, const u16* __restrict__ wpth,
    float* __restrict__ out)
{
    const int bm = blockIdx.x * 16;            // 512 blocks
    const int tid = threadIdx.x;
    const int wv8 = tid >> 6, lane = tid & 63;
    const int wc = wv8;                        // wave col-group (16 cols)
    const int lr = lane & 15, quad = lane >> 4;

    __shared__ u16 At2[2][16][520];            // 33.3KB

    #define G2STAGE(KS, SLOT) do {                                            \
        _Pragma("unroll")                                                     \
        for (int _t = 0; _t < 2; ++_t) {                                      \
            const int _r = wv8 * 2 + _t;                                      \
            gload_lds16(ah + (size_t)(bm + _r) * AH_LD + (KS) * 512           \
                        + lane * 8, &At2[(SLOT)][_r][0]);                     \
        }                                                                     \
    } while (0)

    f32x4 acc = {0.f, 0.f, 0.f, 0.f};

    G2STAGE(0, 0);

    #pragma unroll 1
    for (int ks = 0; ks < 4; ++ks) {
        const int slot = ks & 1;
        __asm__ volatile("s_waitcnt vmcnt(0)" ::: "memory");
        __asm__ volatile("s_barrier" ::: "memory");  // stage(ks) done everywhere
        if (ks < 3) G2STAGE(ks + 1, slot ^ 1);       // slot^1 free (ks-1 done)

        const u16* wbase = wpth + (size_t)(wc * 16 + lr) * WP_LD
                           + ks * 512 + quad * 8;
        #pragma unroll
        for (int s = 0; s < 16; ++s) {
            short8 wf = *(const short8*)(wbase + s * 32);
            short8 af = *(const short8*)&At2[slot][lr][s * 32 + quad * 8];
            acc = MFMA16(wf, af, acc, 0, 0, 0);
        }
    }
    #undef G2STAGE

    __asm__ volatile("s_waitcnt vmcnt(0)" ::: "memory");

    {
        float* orow = out + (size_t)(bm + lr) * DIM_ + wc * 16 + quad * 4;
        *(float4*)orow = *(float4*)&acc;
    }
}

// ---------- launch ----------------------------------------------------------
extern "C" void kernel_launch(void* const* d_in, const int* in_sizes, int n_in,
                              void* d_out, int out_size, void* d_ws, size_t ws_size,
                              hipStream_t stream)
{
    const float* x     = (const float*)d_in[0];
    const float* Wqkv  = (const float*)d_in[1];
    const float* Wproj = (const float*)d_in[2];
    float* out = (float*)d_out;

    u16* xh   = (u16*)d_ws;
    u16* wth  = xh   + (size_t)NX;
    u16* wpth = wth  + (size_t)NWQ;
    u16* qkvb = wpth + (size_t)DIM_ * WP_LD;                 // 128*2112
    u16* vg   = qkvb + (size_t)8192 * QB_LD;                 // 8192*3136
    u16* ahp  = vg   + (size_t)BATCH_ * KVH_ * DIM_ * VG_LD; // 16*128*2112

    prep<<<1024 + 640, 256, 0, stream>>>(x, Wqkv, Wproj, xh, wth, wpth);

    gemm1_mfma<<<dim3(12, 64), 256, 0, stream>>>(xh, wth, qkvb, vg);

    attn_mfma<<<1024, 512, 0, stream>>>(qkvb, vg, ahp);

    gemm2_mfma<<<8192 / 16, 512, 0, stream>>>(ahp, wpth, out);
}